// Round 8
// baseline (599.416 us; speedup 1.0000x reference)
//
#include <hip/hip_runtime.h>
#include <math.h>

#define NMOL 512
#define NATOM 64
#define NFLAT (NMOL*NATOM)
#define AEVL 384
#define FK 448           // fp16 feature row: 384 aev | 32 qraev | q | esp | 30 pad(0)
#define D0 256
#define D1 192
#define D2 160
#define MPAD 33024

typedef _Float16 h8 __attribute__((ext_vector_type(8)));
typedef float    f4 __attribute__((ext_vector_type(4)));

__constant__ float c_sigma[8] = {0.5515909f,1.8886297f,1.3225029f,1.2316629f,
                                 2.1884933f,1.7750372f,1.3677907f,1.3820058f};

__device__ __forceinline__ float wsum(float v){
  #pragma unroll
  for (int o=1;o<64;o<<=1) v += __shfl_xor(v,o);
  return v;
}

// ---------------- AEV -> fp16 feature rows (tail 384..447 zeroed) ----------------
__global__ void cvt_aev_kernel(const float* __restrict__ aev, _Float16* __restrict__ feat){
  int atom = blockIdx.x*4 + (threadIdx.x>>6);
  int c = threadIdx.x & 63;
  if (c >= 56) return;
  int k8 = c*8;
  h8 o;
  if (k8 < AEVL){
    const f4* s = reinterpret_cast<const f4*>(aev + (size_t)atom*AEVL + k8);
    f4 a = s[0], b = s[1];
    o[0]=(_Float16)a[0]; o[1]=(_Float16)a[1]; o[2]=(_Float16)a[2]; o[3]=(_Float16)a[3];
    o[4]=(_Float16)b[0]; o[5]=(_Float16)b[1]; o[6]=(_Float16)b[2]; o[7]=(_Float16)b[3];
  } else {
    #pragma unroll
    for (int i=0;i<8;i++) o[i] = (_Float16)0.f;
  }
  *reinterpret_cast<h8*>(feat + (size_t)atom*FK + k8) = o;
}

// ---------------- W [4][K][N] f32 -> Wt [4][Npad][Kpad] fp16 (transposed, zero-padded) ----------------
__global__ void wtrans_kernel(const float* __restrict__ W, _Float16* __restrict__ Wt,
                              int K, int N, int Npad, int Kpad){
  int s = blockIdx.z;
  int k0 = blockIdx.x*64, n0 = blockIdx.y*32;
  __shared__ float ld[64][33];
  int t = threadIdx.x;
  int nn = t & 31, kk0 = t >> 5;
  #pragma unroll
  for (int i=0;i<8;i++){
    int kk = kk0 + i*8;
    int gk = k0+kk, gn = n0+nn;
    ld[kk][nn] = (gk < K && gn < N) ? W[((size_t)s*K + gk)*N + gn] : 0.f;
  }
  __syncthreads();
  int n_l = t>>3, kc = (t&7)*8;
  h8 o;
  #pragma unroll
  for (int j=0;j<8;j++) o[j] = (_Float16)ld[kc+j][n_l];
  *reinterpret_cast<h8*>(Wt + ((size_t)s*Npad + n0+n_l)*Kpad + k0 + kc) = o;
}

// ---------------- distances + per-atom species data + per-molecule histogram ----------------
__global__ void prep_kernel(const int* __restrict__ species,
                            const float* __restrict__ coord,
                            float* __restrict__ dbuf, float* __restrict__ sig,
                            float* __restrict__ invj, float* __restrict__ pmf,
                            int* __restrict__ blkhist){
  int m = blockIdx.x, t = threadIdx.x;
  __shared__ float c[192];
  if (t < 192) c[t] = coord[m*192 + t];
  __syncthreads();
  #pragma unroll
  for (int k=0;k<16;k++){
    int p = t + 256*k;
    int i = p >> 6, j = p & 63;
    float dx=c[i*3]-c[j*3], dy=c[i*3+1]-c[j*3+1], dz=c[i*3+2]-c[j*3+2];
    dbuf[m*4096 + p] = sqrtf(dx*dx+dy*dy+dz*dz + 1e-16f) / 0.529177249f;
  }
  if (t < 64){
    int g = m*64+t;
    int s = species[g];
    float sg = c_sigma[s < 0 ? 7 : s];
    sig[g]  = sg;
    invj[g] = 1.7724539f * sg;   // sqrt(pi) fp32
    pmf[g]  = (s>=0) ? 1.f : 0.f;
    #pragma unroll
    for (int sp=0;sp<4;sp++){
      unsigned long long mask = __ballot(s==sp);
      if (t==0) blkhist[m*4+sp] = __popcll(mask);
    }
  }
}

// ---------------- plan: totals, 64-aligned bases, tile bases, per-molecule offsets ----------------
// meta: [0..3] counts, [4..8] base(64-aligned, [8]=total rows), [9..13] tile_base ([13]=total tiles)
__global__ void plan_kernel(const int* __restrict__ blkhist, int* __restrict__ meta,
                            int* __restrict__ blkoff){
  __shared__ int tot[4], base[4];
  int t = threadIdx.x;
  if (t < 4){
    int sum = 0;
    for (int m=0;m<NMOL;m++) sum += blkhist[m*4+t];
    tot[t] = sum;
  }
  __syncthreads();
  if (t == 0){
    int b=0, tb=0;
    meta[4]=0; meta[9]=0;
    for (int s=0;s<4;s++){
      meta[s] = tot[s];
      base[s] = b;
      int tiles = (tot[s]+63)>>6;
      b  += tiles<<6;  tb += tiles;
      meta[5+s]  = b;  meta[10+s] = tb;
    }
  }
  __syncthreads();
  if (t < 4){
    int run = base[t];
    for (int m=0;m<NMOL;m++){ blkoff[m*4+t] = run; run += blkhist[m*4+t]; }
  }
}

// ---------------- deterministic atomic-free scatter ----------------
__global__ void scatter_kernel(const int* __restrict__ species,
                               const int* __restrict__ blkoff,
                               int* __restrict__ idxarr){
  int m = blockIdx.x, a = threadIdx.x, g = m*64+a;
  int s = species[g];
  unsigned long long below = (1ull<<a) - 1ull;
  #pragma unroll
  for (int sp=0;sp<4;sp++){
    unsigned long long mask = __ballot(s==sp);
    if (s==sp){
      int rank = __popcll(mask & below);
      idxarr[blkoff[m*4+sp] + rank] = g;
    }
  }
}

// ---------------- fp16 MFMA GEMM, operands direct from global (no LDS, no barriers) ----------------
// Block 256 = 4 waves; wave w: rows [row0+w*16, +16) x cols [n0, n0+64).
// Per k-step: 1 A-frag + 4 B-frag b128 loads + 4 MFMA. Wt is [4][Npad][Kpad] fp16 zero-padded.
template<int GATHER>
__launch_bounds__(256)
__global__ void gemm_mfma(const _Float16* __restrict__ Ah,    // [rows][Kpad]   (GATHER=0)
                          const _Float16* __restrict__ feat,  // [NFLAT][FK]    (GATHER=1)
                          const int* __restrict__ idxarr,
                          const int* __restrict__ meta,
                          const _Float16* __restrict__ Wt,    // [4][Npad][Kpad]
                          const float* __restrict__ Ball,     // [4][N]
                          _Float16* __restrict__ C,           // [rows][N]
                          int Kpad, int N, int Npad, int act){
  int t = blockIdx.x;
  if (t >= meta[13]) return;
  int s = 0;
  while (s < 3 && t >= meta[10+s]) s++;
  int trow = t - meta[9+s];
  int row0 = meta[4+s] + (trow<<6);
  int mrem = meta[s] - (trow<<6); if (mrem > 64) mrem = 64;
  int n0 = blockIdx.y << 6;

  int tid = threadIdx.x;
  int w = tid>>6, l = tid&63;
  int lr16 = l&15, lg = l>>4;

  int arow = row0 + w*16 + lr16;
  int amax = row0 + mrem - 1;
  if (arow > amax) arow = amax;          // clamp (store is masked)
  const _Float16* ap;
  if (GATHER) ap = feat + (size_t)idxarr[arow]*FK + lg*8;
  else        ap = Ah + (size_t)arow*Kpad + lg*8;

  const _Float16* bp = Wt + ((size_t)s*Npad + n0 + lr16)*Kpad + lg*8;
  const size_t bs16 = (size_t)16*Kpad;

  f4 acc0 = {0.f,0.f,0.f,0.f}, acc1 = acc0, acc2 = acc0, acc3 = acc0;
  #pragma unroll 2
  for (int k0=0; k0<Kpad; k0+=32){
    h8 af = *reinterpret_cast<const h8*>(ap + k0);
    h8 b0 = *reinterpret_cast<const h8*>(bp + k0);
    h8 b1 = *reinterpret_cast<const h8*>(bp + bs16 + k0);
    h8 b2 = *reinterpret_cast<const h8*>(bp + 2*bs16 + k0);
    h8 b3 = *reinterpret_cast<const h8*>(bp + 3*bs16 + k0);
    acc0 = __builtin_amdgcn_mfma_f32_16x16x32_f16(af, b0, acc0, 0, 0, 0);
    acc1 = __builtin_amdgcn_mfma_f32_16x16x32_f16(af, b1, acc1, 0, 0, 0);
    acc2 = __builtin_amdgcn_mfma_f32_16x16x32_f16(af, b2, acc2, 0, 0, 0);
    acc3 = __builtin_amdgcn_mfma_f32_16x16x32_f16(af, b3, acc3, 0, 0, 0);
  }
  // epilogue: C/D layout col=lane&15, row=(lane>>4)*4+reg (HW-verified)
  const float* bias = Ball + s*N;
  f4 accs[4] = {acc0, acc1, acc2, acc3};
  #pragma unroll
  for (int c=0;c<4;c++){
    int col = n0 + c*16 + lr16;
    if (col >= N) continue;
    float bsv = bias[col];
    #pragma unroll
    for (int r=0;r<4;r++){
      int lrow = w*16 + lg*4 + r;
      if (lrow >= mrem) continue;
      float vv = accs[c][r] + bsv;
      if (act) vv = vv > 0.f ? vv : 0.1f*expm1f(vv*10.f);
      C[(size_t)(row0+lrow)*N + col] = (_Float16)vv;
    }
  }
}

// ---------------- output layer: 160 -> 1 dot per row (fp16 h), scatter to atom ----------------
__global__ void layer3_kernel(const _Float16* __restrict__ h2,
                              const int* __restrict__ idxarr,
                              const int* __restrict__ meta,
                              const float* __restrict__ W3,  // [4][160]
                              const float* __restrict__ b3,  // [4]
                              float* __restrict__ outv){
  int row = blockIdx.x*4 + (threadIdx.x>>6);
  int lane = threadIdx.x & 63;
  if (row >= meta[8]) return;
  int s = 0;
  while (s < 3 && row >= meta[5+s]) s++;
  int lrow = row - meta[4+s];
  if (lrow >= meta[s]) return;
  const _Float16* h = h2 + (size_t)row*D2;
  const float* w = W3 + s*D2;
  float v = (float)h[lane]*w[lane] + (float)h[lane+64]*w[lane+64];
  if (lane < 32) v += (float)h[lane+128]*w[lane+128];
  v = wsum(v);
  if (lane == 0) outv[idxarr[row]] = v + b3[s];
}

// ---------------- fused charge iteration: qupdate + esp + qraev -> fp16 feature slots ----------------
__global__ void iter_kernel(const float* __restrict__ chi, const float* __restrict__ invj,
                            const float* __restrict__ pmf, const float* __restrict__ netq,
                            const float* __restrict__ dbuf, const float* __restrict__ sig,
                            float* __restrict__ q, _Float16* __restrict__ feat){
  int m = blockIdx.x, tid = threadIdx.x;
  int i = tid & 63, w = tid >> 6;
  __shared__ float qs[64], pms[64], sg2[64];
  __shared__ float esp4[4][64];
  if (tid < 64){
    int g = m*64 + i;
    float pm = pmf[g], ij = invj[g];
    float c = pm > 0.f ? chi[g] : 0.f;
    float num = wsum(c*ij);
    float den = wsum(ij*pm);
    float corr = (netq[m] + num) / den;
    float qa = -ij*(c - corr)*pm;
    q[g] = qa;
    feat[(size_t)g*FK + 416] = (_Float16)qa;
    qs[i] = qa; pms[i] = pm;
    float s0 = sig[g]; sg2[i] = s0*s0;
  }
  __syncthreads();
  const float* dr = dbuf + (size_t)m*4096;
  // esp: each wave handles 16 j's per atom
  {
    float si2 = sg2[i];
    float acc = 0.f;
    for (int jj=0;jj<16;jj++){
      int j = w*16 + jj;
      if (j==i) continue;
      float d = dr[j*64 + i];
      float ss = fmaxf(si2 + sg2[j], 1e-8f);
      acc += qs[j]*pms[j]*erff(d/sqrtf(2.f*ss))/d;
    }
    esp4[w][i] = acc;
  }
  __syncthreads();
  if (tid < 64){
    int g = m*64+i;
    feat[(size_t)g*FK + 417] = (_Float16)((esp4[0][i]+esp4[1][i]+esp4[2][i]+esp4[3][i]) * pms[i]);
  }
  // qraev: wave w handles r-bins [w*8, w*8+8)
  float pmi = pms[i];
  float acc[8] = {0.f,0.f,0.f,0.f,0.f,0.f,0.f,0.f};
  const float step = 8.2f/31.f;
  float rbase = 0.8f + (w*8)*step;
  for (int j=0;j<64;j++){
    if (j==i) continue;
    float d = dr[j*64+i];
    float wq = 0.f;
    if (d < 10.f) wq = 0.25f*(0.5f*cosf(0.31415926535f*d)+0.5f)*qs[j]*pms[j]*pmi;
    if (wq != 0.f){
      #pragma unroll
      for (int r=0;r<8;r++){
        float dd = d - (rbase + r*step);
        acc[r] += wq*expf(-4.f*dd*dd);
      }
    }
  }
  _Float16* xr = feat + (size_t)(m*64+i)*FK + 384 + w*8;
  #pragma unroll
  for (int r=0;r<8;r++) xr[r] = (_Float16)acc[r];
}

// ---------------- screened Coulomb + energy + outputs ----------------
__global__ void final_kernel(const float* __restrict__ dbuf, const float* __restrict__ q,
                             const float* __restrict__ pmf, const float* __restrict__ ae,
                             const int* __restrict__ species, float* __restrict__ out){
  int m = blockIdx.x, a = threadIdx.x, g = m*64+a;
  __shared__ float qs[64], pms[64];
  qs[a]=q[g]; pms[a]=pmf[g];
  __syncthreads();
  float acc=0.f;
  const float* dr = dbuf + (size_t)m*4096;
  for (int b=0;b<64;b++){
    if (b==a) continue;
    float d = dr[b*64+a];
    float sgm = 1.f/(1.f+expf(-(d-2.2f)*8.5f));
    acc += qs[b]*pms[b]*sgm/d;
  }
  float e = 0.5f*qs[a]*pms[a]*acc;          // triu(k=1) sum of symmetric matrix
  float aea = pms[a]>0.f ? ae[g] : 0.f;
  float tot = wsum(e + aea);
  if (a == 0) out[NFLAT + m] = tot;
  out[g] = (float)species[g];
  out[NFLAT + NMOL + g] = qs[a];
}

extern "C" void kernel_launch(void* const* d_in, const int* in_sizes, int n_in,
                              void* d_out, int out_size, void* d_ws, size_t ws_size,
                              hipStream_t stream){
  const int*   species = (const int*)d_in[0];
  const float* coord   = (const float*)d_in[1];
  const float* netq    = (const float*)d_in[2];
  const float* aev     = (const float*)d_in[3];
  const float* cW[4] = {(const float*)d_in[4],(const float*)d_in[6],(const float*)d_in[8],(const float*)d_in[10]};
  const float* cB[4] = {(const float*)d_in[5],(const float*)d_in[7],(const float*)d_in[9],(const float*)d_in[11]};
  const float* aW[4] = {(const float*)d_in[12],(const float*)d_in[14],(const float*)d_in[16],(const float*)d_in[18]};
  const float* aB[4] = {(const float*)d_in[13],(const float*)d_in[15],(const float*)d_in[17],(const float*)d_in[19]};

  // workspace layout (float units; fp16 regions counted as elems/2, all 16B-aligned)
  float* f = (float*)d_ws;
  size_t o = 0;
  float* dbuf  = f + o; o += (size_t)NMOL*4096;
  float* sig   = f + o; o += NFLAT;
  float* invj  = f + o; o += NFLAT;
  float* pmf   = f + o; o += NFLAT;
  float* q     = f + o; o += NFLAT;
  float* chi   = f + o; o += NFLAT;
  _Float16* feat = (_Float16*)(f + o); o += (size_t)NFLAT*FK/2;
  _Float16* h0h  = (_Float16*)(f + o); o += (size_t)MPAD*D0/2;
  _Float16* h1h  = (_Float16*)(f + o); o += (size_t)MPAD*D1/2;
  _Float16* h2h  = h0h;   // layer2 writes over h0 (already consumed)
  _Float16* wt[6]; // chi L0,L1,L2, ani L0,L1,L2  -- [4][Npad][Kpad]
  const int KP[3] = {448, 256, 192};
  const int NP[3] = {256, 192, 192};
  for (int i=0;i<6;i++){
    wt[i] = (_Float16*)(f + o);
    o += (size_t)4*NP[i%3]*KP[i%3]/2;
  }
  int* meta    = (int*)(f + o); o += 64;
  int* idxarr  = (int*)(f + o); o += MPAD;
  int* blkhist = (int*)(f + o); o += NMOL*4;
  int* blkoff  = (int*)(f + o); o += NMOL*4;

  // ---- one-time prep (per launch) ----
  cvt_aev_kernel<<<dim3(NFLAT/4), 256, 0, stream>>>(aev, feat);
  for (int i=0;i<6;i++){
    const float* Wsrc = (i<3) ? cW[i] : aW[i-3];
    int li = i%3;
    int K = (li==0) ? 418 : (li==1 ? D0 : D1);
    int N = (li==0) ? D0  : (li==1 ? D1 : D2);
    wtrans_kernel<<<dim3(KP[li]/64, NP[li]/32, 4), 256, 0, stream>>>(Wsrc, wt[i], K, N, NP[li], KP[li]);
  }
  prep_kernel<<<dim3(NMOL), 256, 0, stream>>>(species, coord, dbuf, sig, invj, pmf, blkhist);
  plan_kernel<<<dim3(1), 64, 0, stream>>>(blkhist, meta, blkoff);
  scatter_kernel<<<dim3(NMOL), 64, 0, stream>>>(species, blkoff, idxarr);

  for (int pass=0; pass<3; ++pass){
    int wb = (pass<2) ? 0 : 3;
    const float* const* Bp = (pass<2) ? cB : aB;
    gemm_mfma<1><<<dim3(516,4), 256, 0, stream>>>(nullptr, feat, idxarr, meta,
                                                  wt[wb+0], Bp[0], h0h, KP[0], D0, NP[0], 1);
    gemm_mfma<0><<<dim3(516,3), 256, 0, stream>>>(h0h, nullptr, idxarr, meta,
                                                  wt[wb+1], Bp[1], h1h, KP[1], D1, NP[1], 1);
    gemm_mfma<0><<<dim3(516,3), 256, 0, stream>>>(h1h, nullptr, idxarr, meta,
                                                  wt[wb+2], Bp[2], h2h, KP[2], D2, NP[2], 1);
    layer3_kernel<<<dim3(MPAD/4), 256, 0, stream>>>(h2h, idxarr, meta, (pass<2)?cW[3]:aW[3],
                                                    (pass<2)?cB[3]:aB[3], chi);
    if (pass < 2)
      iter_kernel<<<dim3(NMOL), 256, 0, stream>>>(chi, invj, pmf, netq, dbuf, sig, q, feat);
  }
  final_kernel<<<dim3(NMOL), 64, 0, stream>>>(dbuf, q, pmf, chi, species, (float*)d_out);
}

// Round 9
// 508.687 us; speedup vs baseline: 1.1784x; 1.1784x over previous
//
#include <hip/hip_runtime.h>
#include <math.h>

#define NMOL 512
#define NATOM 64
#define NFLAT (NMOL*NATOM)
#define AEVL 384
#define FK 448           // fp16 feature row: 384 aev | 32 qraev | q | esp | 30 pad(0)
#define D0 256
#define D1 192
#define D2 160
#define MPAD 33024

typedef _Float16 h8 __attribute__((ext_vector_type(8)));
typedef float    f4 __attribute__((ext_vector_type(4)));

__constant__ float c_sigma[8] = {0.5515909f,1.8886297f,1.3225029f,1.2316629f,
                                 2.1884933f,1.7750372f,1.3677907f,1.3820058f};

__device__ __forceinline__ float wsum(float v){
  #pragma unroll
  for (int o=1;o<64;o<<=1) v += __shfl_xor(v,o);
  return v;
}

// ---------------- AEV -> fp16 feature rows (tail 384..447 zeroed) ----------------
__global__ void cvt_aev_kernel(const float* __restrict__ aev, _Float16* __restrict__ feat){
  int atom = blockIdx.x*4 + (threadIdx.x>>6);
  int c = threadIdx.x & 63;
  if (c >= 56) return;
  int k8 = c*8;
  h8 o;
  if (k8 < AEVL){
    const f4* s = reinterpret_cast<const f4*>(aev + (size_t)atom*AEVL + k8);
    f4 a = s[0], b = s[1];
    o[0]=(_Float16)a[0]; o[1]=(_Float16)a[1]; o[2]=(_Float16)a[2]; o[3]=(_Float16)a[3];
    o[4]=(_Float16)b[0]; o[5]=(_Float16)b[1]; o[6]=(_Float16)b[2]; o[7]=(_Float16)b[3];
  } else {
    #pragma unroll
    for (int i=0;i<8;i++) o[i] = (_Float16)0.f;
  }
  *reinterpret_cast<h8*>(feat + (size_t)atom*FK + k8) = o;
}

// ---- W [4][K][N] f32 -> Wt [4][KT][N][32] fp16 (k-step tiles contiguous, zero-padded) ----
__global__ void wtrans_kernel(const float* __restrict__ W, _Float16* __restrict__ Wt,
                              int K, int N, int KT){
  int pair = blockIdx.x*256 + threadIdx.x;
  if (pair >= N*KT) return;
  int col = pair % N;          // consecutive threads -> consecutive cols (coalesced reads)
  int kb  = pair / N;
  int s = blockIdx.y;
  h8 o[4];
  #pragma unroll
  for (int g=0; g<4; ++g){
    #pragma unroll
    for (int e=0; e<8; ++e){
      int gk = kb*32 + g*8 + e;
      float v = (gk < K) ? W[((size_t)s*K + gk)*N + col] : 0.f;
      o[g][e] = (_Float16)v;
    }
  }
  _Float16* dst = Wt + (((size_t)s*KT + kb)*N + col)*32;
  #pragma unroll
  for (int g=0; g<4; ++g) *reinterpret_cast<h8*>(dst + g*8) = o[g];
}

// ---------------- distances + per-atom species data + per-molecule histogram ----------------
__global__ void prep_kernel(const int* __restrict__ species,
                            const float* __restrict__ coord,
                            float* __restrict__ dbuf, float* __restrict__ sig,
                            float* __restrict__ invj, float* __restrict__ pmf,
                            int* __restrict__ blkhist){
  int m = blockIdx.x, t = threadIdx.x;
  __shared__ float c[192];
  if (t < 192) c[t] = coord[m*192 + t];
  __syncthreads();
  #pragma unroll
  for (int k=0;k<16;k++){
    int p = t + 256*k;
    int i = p >> 6, j = p & 63;
    float dx=c[i*3]-c[j*3], dy=c[i*3+1]-c[j*3+1], dz=c[i*3+2]-c[j*3+2];
    dbuf[m*4096 + p] = sqrtf(dx*dx+dy*dy+dz*dz + 1e-16f) / 0.529177249f;
  }
  if (t < 64){
    int g = m*64+t;
    int s = species[g];
    float sg = c_sigma[s < 0 ? 7 : s];
    sig[g]  = sg;
    invj[g] = 1.7724539f * sg;   // sqrt(pi) fp32
    pmf[g]  = (s>=0) ? 1.f : 0.f;
    #pragma unroll
    for (int sp=0;sp<4;sp++){
      unsigned long long mask = __ballot(s==sp);
      if (t==0) blkhist[m*4+sp] = __popcll(mask);
    }
  }
}

// ---------------- plan: totals, 64-aligned bases, tile bases, per-molecule offsets ----------------
// meta: [0..3] counts, [4..8] base(64-aligned, [8]=total rows), [9..13] tile_base ([13]=total tiles)
__global__ void plan_kernel(const int* __restrict__ blkhist, int* __restrict__ meta,
                            int* __restrict__ blkoff){
  __shared__ int tot[4], base[4];
  int t = threadIdx.x;
  if (t < 4){
    int sum = 0;
    for (int m=0;m<NMOL;m++) sum += blkhist[m*4+t];
    tot[t] = sum;
  }
  __syncthreads();
  if (t == 0){
    int b=0, tb=0;
    meta[4]=0; meta[9]=0;
    for (int s=0;s<4;s++){
      meta[s] = tot[s];
      base[s] = b;
      int tiles = (tot[s]+63)>>6;
      b  += tiles<<6;  tb += tiles;
      meta[5+s]  = b;  meta[10+s] = tb;
    }
  }
  __syncthreads();
  if (t < 4){
    int run = base[t];
    for (int m=0;m<NMOL;m++){ blkoff[m*4+t] = run; run += blkhist[m*4+t]; }
  }
}

// ---------------- deterministic atomic-free scatter ----------------
__global__ void scatter_kernel(const int* __restrict__ species,
                               const int* __restrict__ blkoff,
                               int* __restrict__ idxarr){
  int m = blockIdx.x, a = threadIdx.x, g = m*64+a;
  int s = species[g];
  unsigned long long below = (1ull<<a) - 1ull;
  #pragma unroll
  for (int sp=0;sp<4;sp++){
    unsigned long long mask = __ballot(s==sp);
    if (s==sp){
      int rank = __popcll(mask & below);
      idxarr[blkoff[m*4+sp] + rank] = g;
    }
  }
}

// ---------------- fp16 MFMA GEMM: 64-row block x ALL N cols, LDS-staged B, dbuf pipeline ----
// 4 waves; wave w: rows [row0+w*16, +16) x N cols. Per k-step: 1 A-load + NC MFMA.
// B tile [N][32] staged from contiguous Wt[s][kb][N][32] -> LDS [N][36] (uniform banks).
template<int GATHER, int NC, int KT>   // N = NC*16, Kpad = KT*32
__launch_bounds__(256)
__global__ void gemm_lds(const _Float16* __restrict__ Ah,    // [rows][Kpad]  (GATHER=0)
                         const _Float16* __restrict__ feat,  // [NFLAT][FK]   (GATHER=1)
                         const int* __restrict__ idxarr,
                         const int* __restrict__ meta,
                         const _Float16* __restrict__ Wt,    // [4][KT][N][32]
                         const float* __restrict__ Ball,     // [4][N]
                         _Float16* __restrict__ C,           // [rows][N]
                         int act){
  constexpr int N = NC*16;
  int t = blockIdx.x;
  if (t >= meta[13]) return;
  int s = 0;
  while (s < 3 && t >= meta[10+s]) s++;
  int trow = t - meta[9+s];
  int row0 = meta[4+s] + (trow<<6);
  int mrem = meta[s] - (trow<<6); if (mrem > 64) mrem = 64;

  __shared__ _Float16 Bs[2][N][36];

  int tid = threadIdx.x;
  int w = tid>>6, l = tid&63;
  int lr16 = l&15, lg = l>>4;

  int arow = row0 + w*16 + lr16;
  int amax = row0 + mrem - 1;
  if (arow > amax) arow = amax;          // clamp (store is masked)
  const _Float16* ap;
  if (GATHER) ap = feat + (size_t)idxarr[arow]*FK + lg*8;
  else        ap = Ah + (size_t)arow*(KT*32) + lg*8;

  const _Float16* W0 = Wt + (size_t)s*KT*N*32;

  f4 acc[NC];
  #pragma unroll
  for (int c=0;c<NC;c++){ acc[c][0]=0.f; acc[c][1]=0.f; acc[c][2]=0.f; acc[c][3]=0.f; }

  // ---- prologue: stage k-step 0 ----
  h8 rS[4];
  #pragma unroll
  for (int i=0;i<4;++i){
    int j = tid + i*256;
    if (j < N*4) rS[i] = *reinterpret_cast<const h8*>(W0 + j*8);
  }
  h8 aR = *reinterpret_cast<const h8*>(ap);
  #pragma unroll
  for (int i=0;i<4;++i){
    int j = tid + i*256;
    if (j < N*4) *reinterpret_cast<h8*>(&Bs[0][j>>2][(j&3)*8]) = rS[i];
  }
  __syncthreads();

  int cur = 0;
  for (int kt=0; kt<KT; ++kt){
    h8 a = aR;
    if (kt+1 < KT){
      // issue next-step stage loads first, then next A (so ds_write's wait excludes A)
      const _Float16* src = W0 + (size_t)(kt+1)*N*32;
      #pragma unroll
      for (int i=0;i<4;++i){
        int j = tid + i*256;
        if (j < N*4) rS[i] = *reinterpret_cast<const h8*>(src + j*8);
      }
      aR = *reinterpret_cast<const h8*>(ap + (kt+1)*32);
    }
    // compute on buf[cur]
    #pragma unroll
    for (int c=0;c<NC;c++){
      h8 bf = *reinterpret_cast<const h8*>(&Bs[cur][c*16 + lr16][lg*8]);
      acc[c] = __builtin_amdgcn_mfma_f32_16x16x32_f16(a, bf, acc[c], 0, 0, 0);
    }
    if (kt+1 < KT){
      #pragma unroll
      for (int i=0;i<4;++i){
        int j = tid + i*256;
        if (j < N*4) *reinterpret_cast<h8*>(&Bs[cur^1][j>>2][(j&3)*8]) = rS[i];
      }
      __syncthreads();
      cur ^= 1;
    }
  }

  // ---- epilogue: C/D layout col=lane&15, row=(lane>>4)*4+reg (HW-verified) ----
  const float* bias = Ball + s*N;
  #pragma unroll
  for (int c=0;c<NC;c++){
    int col = c*16 + lr16;
    float bsv = bias[col];
    #pragma unroll
    for (int r=0;r<4;r++){
      int lrow = w*16 + lg*4 + r;
      if (lrow >= mrem) continue;
      float vv = acc[c][r] + bsv;
      if (act) vv = vv > 0.f ? vv : 0.1f*expm1f(vv*10.f);
      C[(size_t)(row0+lrow)*N + col] = (_Float16)vv;
    }
  }
}

// ---------------- output layer: 160 -> 1 dot per row (fp16 h), scatter to atom ----------------
__global__ void layer3_kernel(const _Float16* __restrict__ h2,
                              const int* __restrict__ idxarr,
                              const int* __restrict__ meta,
                              const float* __restrict__ W3,  // [4][160]
                              const float* __restrict__ b3,  // [4]
                              float* __restrict__ outv){
  int row = blockIdx.x*4 + (threadIdx.x>>6);
  int lane = threadIdx.x & 63;
  if (row >= meta[8]) return;
  int s = 0;
  while (s < 3 && row >= meta[5+s]) s++;
  int lrow = row - meta[4+s];
  if (lrow >= meta[s]) return;
  const _Float16* h = h2 + (size_t)row*D2;
  const float* w = W3 + s*D2;
  float v = (float)h[lane]*w[lane] + (float)h[lane+64]*w[lane+64];
  if (lane < 32) v += (float)h[lane+128]*w[lane+128];
  v = wsum(v);
  if (lane == 0) outv[idxarr[row]] = v + b3[s];
}

// ---------------- fused charge iteration: qupdate + esp + qraev -> fp16 feature slots ----------------
__global__ void iter_kernel(const float* __restrict__ chi, const float* __restrict__ invj,
                            const float* __restrict__ pmf, const float* __restrict__ netq,
                            const float* __restrict__ dbuf, const float* __restrict__ sig,
                            float* __restrict__ q, _Float16* __restrict__ feat){
  int m = blockIdx.x, tid = threadIdx.x;
  int i = tid & 63, w = tid >> 6;
  __shared__ float qs[64], pms[64], sg2[64];
  __shared__ float esp4[4][64];
  if (tid < 64){
    int g = m*64 + i;
    float pm = pmf[g], ij = invj[g];
    float c = pm > 0.f ? chi[g] : 0.f;
    float num = wsum(c*ij);
    float den = wsum(ij*pm);
    float corr = (netq[m] + num) / den;
    float qa = -ij*(c - corr)*pm;
    q[g] = qa;
    feat[(size_t)g*FK + 416] = (_Float16)qa;
    qs[i] = qa; pms[i] = pm;
    float s0 = sig[g]; sg2[i] = s0*s0;
  }
  __syncthreads();
  const float* dr = dbuf + (size_t)m*4096;
  // esp: each wave handles 16 j's per atom
  {
    float si2 = sg2[i];
    float acc = 0.f;
    for (int jj=0;jj<16;jj++){
      int j = w*16 + jj;
      if (j==i) continue;
      float d = dr[j*64 + i];
      float ss = fmaxf(si2 + sg2[j], 1e-8f);
      acc += qs[j]*pms[j]*erff(d/sqrtf(2.f*ss))/d;
    }
    esp4[w][i] = acc;
  }
  __syncthreads();
  if (tid < 64){
    int g = m*64+i;
    feat[(size_t)g*FK + 417] = (_Float16)((esp4[0][i]+esp4[1][i]+esp4[2][i]+esp4[3][i]) * pms[i]);
  }
  // qraev: wave w handles r-bins [w*8, w*8+8)
  float pmi = pms[i];
  float acc[8] = {0.f,0.f,0.f,0.f,0.f,0.f,0.f,0.f};
  const float step = 8.2f/31.f;
  float rbase = 0.8f + (w*8)*step;
  for (int j=0;j<64;j++){
    if (j==i) continue;
    float d = dr[j*64+i];
    float wq = 0.f;
    if (d < 10.f) wq = 0.25f*(0.5f*cosf(0.31415926535f*d)+0.5f)*qs[j]*pms[j]*pmi;
    if (wq != 0.f){
      #pragma unroll
      for (int r=0;r<8;r++){
        float dd = d - (rbase + r*step);
        acc[r] += wq*expf(-4.f*dd*dd);
      }
    }
  }
  _Float16* xr = feat + (size_t)(m*64+i)*FK + 384 + w*8;
  #pragma unroll
  for (int r=0;r<8;r++) xr[r] = (_Float16)acc[r];
}

// ---------------- screened Coulomb + energy + outputs ----------------
__global__ void final_kernel(const float* __restrict__ dbuf, const float* __restrict__ q,
                             const float* __restrict__ pmf, const float* __restrict__ ae,
                             const int* __restrict__ species, float* __restrict__ out){
  int m = blockIdx.x, a = threadIdx.x, g = m*64+a;
  __shared__ float qs[64], pms[64];
  qs[a]=q[g]; pms[a]=pmf[g];
  __syncthreads();
  float acc=0.f;
  const float* dr = dbuf + (size_t)m*4096;
  for (int b=0;b<64;b++){
    if (b==a) continue;
    float d = dr[b*64+a];
    float sgm = 1.f/(1.f+expf(-(d-2.2f)*8.5f));
    acc += qs[b]*pms[b]*sgm/d;
  }
  float e = 0.5f*qs[a]*pms[a]*acc;          // triu(k=1) sum of symmetric matrix
  float aea = pms[a]>0.f ? ae[g] : 0.f;
  float tot = wsum(e + aea);
  if (a == 0) out[NFLAT + m] = tot;
  out[g] = (float)species[g];
  out[NFLAT + NMOL + g] = qs[a];
}

extern "C" void kernel_launch(void* const* d_in, const int* in_sizes, int n_in,
                              void* d_out, int out_size, void* d_ws, size_t ws_size,
                              hipStream_t stream){
  const int*   species = (const int*)d_in[0];
  const float* coord   = (const float*)d_in[1];
  const float* netq    = (const float*)d_in[2];
  const float* aev     = (const float*)d_in[3];
  const float* cW[4] = {(const float*)d_in[4],(const float*)d_in[6],(const float*)d_in[8],(const float*)d_in[10]};
  const float* cB[4] = {(const float*)d_in[5],(const float*)d_in[7],(const float*)d_in[9],(const float*)d_in[11]};
  const float* aW[4] = {(const float*)d_in[12],(const float*)d_in[14],(const float*)d_in[16],(const float*)d_in[18]};
  const float* aB[4] = {(const float*)d_in[13],(const float*)d_in[15],(const float*)d_in[17],(const float*)d_in[19]};

  // workspace layout (float units; fp16 regions counted as elems/2, all 16B-aligned)
  float* f = (float*)d_ws;
  size_t o = 0;
  float* dbuf  = f + o; o += (size_t)NMOL*4096;
  float* sig   = f + o; o += NFLAT;
  float* invj  = f + o; o += NFLAT;
  float* pmf   = f + o; o += NFLAT;
  float* q     = f + o; o += NFLAT;
  float* chi   = f + o; o += NFLAT;
  _Float16* feat = (_Float16*)(f + o); o += (size_t)NFLAT*FK/2;
  _Float16* h0h  = (_Float16*)(f + o); o += (size_t)MPAD*D0/2;
  _Float16* h1h  = (_Float16*)(f + o); o += (size_t)MPAD*D1/2;
  _Float16* h2h  = h0h;   // layer2 writes over h0 (already consumed)
  // Wt[i]: [4][KT][N][32] fp16
  const int KT_[3] = {14, 8, 6};
  const int N_[3]  = {D0, D1, D2};
  _Float16* wt[6];
  for (int i=0;i<6;i++){
    wt[i] = (_Float16*)(f + o);
    o += (size_t)4*KT_[i%3]*N_[i%3]*32/2;
  }
  int* meta    = (int*)(f + o); o += 64;
  int* idxarr  = (int*)(f + o); o += MPAD;
  int* blkhist = (int*)(f + o); o += NMOL*4;
  int* blkoff  = (int*)(f + o); o += NMOL*4;

  // ---- one-time prep (per launch) ----
  cvt_aev_kernel<<<dim3(NFLAT/4), 256, 0, stream>>>(aev, feat);
  for (int i=0;i<6;i++){
    const float* Wsrc = (i<3) ? cW[i] : aW[i-3];
    int li = i%3;
    int K = (li==0) ? 418 : (li==1 ? D0 : D1);
    int N = N_[li], KT = KT_[li];
    wtrans_kernel<<<dim3((N*KT+255)/256, 4), 256, 0, stream>>>(Wsrc, wt[i], K, N, KT);
  }
  prep_kernel<<<dim3(NMOL), 256, 0, stream>>>(species, coord, dbuf, sig, invj, pmf, blkhist);
  plan_kernel<<<dim3(1), 64, 0, stream>>>(blkhist, meta, blkoff);
  scatter_kernel<<<dim3(NMOL), 64, 0, stream>>>(species, blkoff, idxarr);

  for (int pass=0; pass<3; ++pass){
    int wb = (pass<2) ? 0 : 3;
    const float* const* Bp = (pass<2) ? cB : aB;
    gemm_lds<1,16,14><<<dim3(516), 256, 0, stream>>>(nullptr, feat, idxarr, meta,
                                                     wt[wb+0], Bp[0], h0h, 1);
    gemm_lds<0,12, 8><<<dim3(516), 256, 0, stream>>>(h0h, nullptr, idxarr, meta,
                                                     wt[wb+1], Bp[1], h1h, 1);
    gemm_lds<0,10, 6><<<dim3(516), 256, 0, stream>>>(h1h, nullptr, idxarr, meta,
                                                     wt[wb+2], Bp[2], h2h, 1);
    layer3_kernel<<<dim3(MPAD/4), 256, 0, stream>>>(h2h, idxarr, meta, (pass<2)?cW[3]:aW[3],
                                                    (pass<2)?cB[3]:aB[3], chi);
    if (pass < 2)
      iter_kernel<<<dim3(NMOL), 256, 0, stream>>>(chi, invj, pmf, netq, dbuf, sig, q, feat);
  }
  final_kernel<<<dim3(NMOL), 64, 0, stream>>>(dbuf, q, pmf, chi, species, (float*)d_out);
}

// Round 10
// 349.097 us; speedup vs baseline: 1.7170x; 1.4572x over previous
//
#include <hip/hip_runtime.h>
#include <math.h>

#define NMOL 512
#define NATOM 64
#define NFLAT (NMOL*NATOM)
#define AEVL 384
#define FK 448           // fp16 feature row: 384 aev | 32 qraev | q | esp | 30 pad(0)
#define D0 256
#define D1 192
#define D2 160
#define MPAD 33024

typedef _Float16 h8 __attribute__((ext_vector_type(8)));
typedef float    f4 __attribute__((ext_vector_type(4)));

__constant__ float c_sigma[8] = {0.5515909f,1.8886297f,1.3225029f,1.2316629f,
                                 2.1884933f,1.7750372f,1.3677907f,1.3820058f};

__device__ __forceinline__ float wsum(float v){
  #pragma unroll
  for (int o=1;o<64;o<<=1) v += __shfl_xor(v,o);
  return v;
}

// ---------------- AEV -> fp16 feature rows (tail 384..447 zeroed) ----------------
__global__ void cvt_aev_kernel(const float* __restrict__ aev, _Float16* __restrict__ feat){
  int atom = blockIdx.x*4 + (threadIdx.x>>6);
  int c = threadIdx.x & 63;
  if (c >= 56) return;
  int k8 = c*8;
  h8 o;
  if (k8 < AEVL){
    const f4* s = reinterpret_cast<const f4*>(aev + (size_t)atom*AEVL + k8);
    f4 a = s[0], b = s[1];
    o[0]=(_Float16)a[0]; o[1]=(_Float16)a[1]; o[2]=(_Float16)a[2]; o[3]=(_Float16)a[3];
    o[4]=(_Float16)b[0]; o[5]=(_Float16)b[1]; o[6]=(_Float16)b[2]; o[7]=(_Float16)b[3];
  } else {
    #pragma unroll
    for (int i=0;i<8;i++) o[i] = (_Float16)0.f;
  }
  *reinterpret_cast<h8*>(feat + (size_t)atom*FK + k8) = o;
}

// ---- W [4][K][N] f32 -> Wt [4][KT][N][32] fp16 (k-step tiles contiguous, zero-padded) ----
__global__ void wtrans_kernel(const float* __restrict__ W, _Float16* __restrict__ Wt,
                              int K, int N, int KT){
  int pair = blockIdx.x*256 + threadIdx.x;
  if (pair >= N*KT) return;
  int col = pair % N;
  int kb  = pair / N;
  int s = blockIdx.y;
  h8 o[4];
  #pragma unroll
  for (int g=0; g<4; ++g){
    #pragma unroll
    for (int e=0; e<8; ++e){
      int gk = kb*32 + g*8 + e;
      float v = (gk < K) ? W[((size_t)s*K + gk)*N + col] : 0.f;
      o[g][e] = (_Float16)v;
    }
  }
  _Float16* dst = Wt + (((size_t)s*KT + kb)*N + col)*32;
  #pragma unroll
  for (int g=0; g<4; ++g) *reinterpret_cast<h8*>(dst + g*8) = o[g];
}

// ---------------- distances + per-atom species data + per-molecule histogram ----------------
__global__ void prep_kernel(const int* __restrict__ species,
                            const float* __restrict__ coord,
                            float* __restrict__ dbuf, float* __restrict__ sig,
                            float* __restrict__ invj, float* __restrict__ pmf,
                            int* __restrict__ blkhist){
  int m = blockIdx.x, t = threadIdx.x;
  __shared__ float c[192];
  if (t < 192) c[t] = coord[m*192 + t];
  __syncthreads();
  #pragma unroll
  for (int k=0;k<16;k++){
    int p = t + 256*k;
    int i = p >> 6, j = p & 63;
    float dx=c[i*3]-c[j*3], dy=c[i*3+1]-c[j*3+1], dz=c[i*3+2]-c[j*3+2];
    dbuf[m*4096 + p] = sqrtf(dx*dx+dy*dy+dz*dz + 1e-16f) / 0.529177249f;
  }
  if (t < 64){
    int g = m*64+t;
    int s = species[g];
    float sg = c_sigma[s < 0 ? 7 : s];
    sig[g]  = sg;
    invj[g] = 1.7724539f * sg;   // sqrt(pi) fp32
    pmf[g]  = (s>=0) ? 1.f : 0.f;
    #pragma unroll
    for (int sp=0;sp<4;sp++){
      unsigned long long mask = __ballot(s==sp);
      if (t==0) blkhist[m*4+sp] = __popcll(mask);
    }
  }
}

// ---------------- plan: totals, 64-aligned bases, tile bases, per-molecule offsets ----------------
// meta: [0..3] counts, [4..8] base(64-aligned, [8]=total rows), [9..13] tile_base ([13]=total tiles)
__global__ void plan_kernel(const int* __restrict__ blkhist, int* __restrict__ meta,
                            int* __restrict__ blkoff){
  __shared__ int tot[4], base[4];
  int t = threadIdx.x;
  if (t < 4){
    int sum = 0;
    for (int m=0;m<NMOL;m++) sum += blkhist[m*4+t];
    tot[t] = sum;
  }
  __syncthreads();
  if (t == 0){
    int b=0, tb=0;
    meta[4]=0; meta[9]=0;
    for (int s=0;s<4;s++){
      meta[s] = tot[s];
      base[s] = b;
      int tiles = (tot[s]+63)>>6;
      b  += tiles<<6;  tb += tiles;
      meta[5+s]  = b;  meta[10+s] = tb;
    }
  }
  __syncthreads();
  if (t < 4){
    int run = base[t];
    for (int m=0;m<NMOL;m++){ blkoff[m*4+t] = run; run += blkhist[m*4+t]; }
  }
}

// ---------------- deterministic atomic-free scatter ----------------
__global__ void scatter_kernel(const int* __restrict__ species,
                               const int* __restrict__ blkoff,
                               int* __restrict__ idxarr){
  int m = blockIdx.x, a = threadIdx.x, g = m*64+a;
  int s = species[g];
  unsigned long long below = (1ull<<a) - 1ull;
  #pragma unroll
  for (int sp=0;sp<4;sp++){
    unsigned long long mask = __ballot(s==sp);
    if (s==sp){
      int rank = __popcll(mask & below);
      idxarr[blkoff[m*4+sp] + rank] = g;
    }
  }
}

// ---- fp16 MFMA GEMM: 64-row x NB-col blocks (grid.y col-split), LDS dbuf pipeline ----
// 4 waves; wave w: rows [row0+w*16,+16) x NB cols. Per k-step: 1 A-load + NCB MFMA/wave.
template<int GATHER, int NCB, int KT>   // NB = NCB*16 cols per block, Kpad = KT*32
__launch_bounds__(256)
__global__ void gemm_cb(const _Float16* __restrict__ Ah,    // [rows][Kpad]  (GATHER=0)
                        const _Float16* __restrict__ feat,  // [NFLAT][FK]   (GATHER=1)
                        const int* __restrict__ idxarr,
                        const int* __restrict__ meta,
                        const _Float16* __restrict__ Wt,    // [4][KT][N][32]
                        const float* __restrict__ Ball,     // [4][N]
                        _Float16* __restrict__ C,           // [rows][N]
                        int N, int act){
  constexpr int NB  = NCB*16;
  constexpr int NCH = NB*4;          // h8 chunks per k-step tile
  int t = blockIdx.x;
  if (t >= meta[13]) return;
  int s = 0;
  while (s < 3 && t >= meta[10+s]) s++;
  int trow = t - meta[9+s];
  int row0 = meta[4+s] + (trow<<6);
  int mrem = meta[s] - (trow<<6); if (mrem > 64) mrem = 64;
  const int c0 = blockIdx.y*NB;

  __shared__ _Float16 Bs[2][NB][36];

  int tid = threadIdx.x;
  int w = tid>>6, l = tid&63;
  int lr16 = l&15, lg = l>>4;

  int arow = row0 + w*16 + lr16;
  int amax = row0 + mrem - 1;
  if (arow > amax) arow = amax;          // clamp (store is masked)
  const _Float16* ap;
  if (GATHER) ap = feat + (size_t)idxarr[arow]*FK + lg*8;
  else        ap = Ah + (size_t)arow*(KT*32) + lg*8;

  const _Float16* W0 = Wt + (size_t)s*KT*N*32 + (size_t)c0*32;

  f4 acc[NCB];
  #pragma unroll
  for (int c=0;c<NCB;c++){ acc[c][0]=0.f; acc[c][1]=0.f; acc[c][2]=0.f; acc[c][3]=0.f; }

  const int j0 = tid, j1 = tid + 256;
  // ---- prologue: stage k-step 0 ----
  h8 r0 = *reinterpret_cast<const h8*>(W0 + (size_t)(j0>>2)*32 + (j0&3)*8);
  h8 r1;
  if (j1 < NCH) r1 = *reinterpret_cast<const h8*>(W0 + (size_t)(j1>>2)*32 + (j1&3)*8);
  h8 aR = *reinterpret_cast<const h8*>(ap);
  *reinterpret_cast<h8*>(&Bs[0][j0>>2][(j0&3)*8]) = r0;
  if (j1 < NCH) *reinterpret_cast<h8*>(&Bs[0][j1>>2][(j1&3)*8]) = r1;
  __syncthreads();

  int cur = 0;
  for (int kt=0; kt<KT; ++kt){
    h8 a = aR;
    if (kt+1 < KT){
      const _Float16* src = W0 + (size_t)(kt+1)*N*32;
      r0 = *reinterpret_cast<const h8*>(src + (size_t)(j0>>2)*32 + (j0&3)*8);
      if (j1 < NCH) r1 = *reinterpret_cast<const h8*>(src + (size_t)(j1>>2)*32 + (j1&3)*8);
      aR = *reinterpret_cast<const h8*>(ap + (kt+1)*32);
    }
    #pragma unroll
    for (int c=0;c<NCB;c++){
      h8 bf = *reinterpret_cast<const h8*>(&Bs[cur][c*16 + lr16][lg*8]);
      acc[c] = __builtin_amdgcn_mfma_f32_16x16x32_f16(a, bf, acc[c], 0, 0, 0);
    }
    if (kt+1 < KT){
      *reinterpret_cast<h8*>(&Bs[cur^1][j0>>2][(j0&3)*8]) = r0;
      if (j1 < NCH) *reinterpret_cast<h8*>(&Bs[cur^1][j1>>2][(j1&3)*8]) = r1;
      __syncthreads();
      cur ^= 1;
    }
  }

  // ---- epilogue: C/D layout col=lane&15, row=(lane>>4)*4+reg (HW-verified) ----
  const float* bias = Ball + s*N;
  #pragma unroll
  for (int c=0;c<NCB;c++){
    int col = c0 + c*16 + lr16;
    float bsv = bias[col];
    #pragma unroll
    for (int r=0;r<4;r++){
      int lrow = w*16 + lg*4 + r;
      if (lrow >= mrem) continue;
      float vv = acc[c][r] + bsv;
      if (act) vv = vv > 0.f ? vv : 0.1f*expm1f(vv*10.f);
      C[(size_t)(row0+lrow)*N + col] = (_Float16)vv;
    }
  }
}

// ---------------- output layer: 160 -> 1 dot per row (fp16 h), scatter to atom ----------------
__global__ void layer3_kernel(const _Float16* __restrict__ h2,
                              const int* __restrict__ idxarr,
                              const int* __restrict__ meta,
                              const float* __restrict__ W3,  // [4][160]
                              const float* __restrict__ b3,  // [4]
                              float* __restrict__ outv){
  int row = blockIdx.x*4 + (threadIdx.x>>6);
  int lane = threadIdx.x & 63;
  if (row >= meta[8]) return;
  int s = 0;
  while (s < 3 && row >= meta[5+s]) s++;
  int lrow = row - meta[4+s];
  if (lrow >= meta[s]) return;
  const _Float16* h = h2 + (size_t)row*D2;
  const float* w = W3 + s*D2;
  float v = (float)h[lane]*w[lane] + (float)h[lane+64]*w[lane+64];
  if (lane < 32) v += (float)h[lane+128]*w[lane+128];
  v = wsum(v);
  if (lane == 0) outv[idxarr[row]] = v + b3[s];
}

// ---- fused charge iteration (512 thr): qupdate + esp(8-way) + qraev(recurrence, 2x4 split) ----
__global__ void iter_kernel(const float* __restrict__ chi, const float* __restrict__ invj,
                            const float* __restrict__ pmf, const float* __restrict__ netq,
                            const float* __restrict__ dbuf, const float* __restrict__ sig,
                            float* __restrict__ q, _Float16* __restrict__ feat){
  int m = blockIdx.x, tid = threadIdx.x;
  int i = tid & 63, w = tid >> 6;   // w in 0..7
  __shared__ float qs[64], pms[64], sg2[64];
  __shared__ float esp8[8][64];
  __shared__ float qr[8][64][8];
  if (tid < 64){
    int g = m*64 + i;
    float pm = pmf[g], ij = invj[g];
    float c = pm > 0.f ? chi[g] : 0.f;
    float num = wsum(c*ij);
    float den = wsum(ij*pm);
    float corr = (netq[m] + num) / den;
    float qa = -ij*(c - corr)*pm;
    q[g] = qa;
    feat[(size_t)g*FK + 416] = (_Float16)qa;
    qs[i] = qa; pms[i] = pm;
    float s0 = sig[g]; sg2[i] = s0*s0;
  }
  __syncthreads();
  const float* dr = dbuf + (size_t)m*4096;
  // esp: thread handles j = w*8 .. w*8+8
  {
    float si2 = sg2[i];
    float acc = 0.f;
    #pragma unroll
    for (int jj=0;jj<8;jj++){
      int j = w*8 + jj;
      if (j==i) continue;
      float d = dr[j*64 + i];
      float ss = fmaxf(si2 + sg2[j], 1e-8f);
      acc += qs[j]*pms[j]*erff(d/sqrtf(2.f*ss))/d;
    }
    esp8[w][i] = acc;
  }
  // qraev: wave w = (jh<<2)|bg: bins [bg*8,bg*8+8), j in [jh*32, jh*32+32)
  {
    const float STEP = 0.264516129f;     // 8.2/31
    const float C2 = 0.7558781f;         // exp(-4*STEP^2)
    const float C1 = 0.5713518f;         // exp(-8*STEP^2)
    int jh = w>>2, bg = w&3;
    float rbase = 0.8f + (bg*8)*STEP;
    float pmi = pms[i];
    float acc[8] = {0.f,0.f,0.f,0.f,0.f,0.f,0.f,0.f};
    for (int jj=0;jj<32;jj++){
      int j = jh*32 + jj;
      if (j==i) continue;
      float d = dr[j*64+i];
      if (d < 10.f){
        float wq = 0.25f*(0.5f*__cosf(0.31415927f*d)+0.5f)*qs[j]*pms[j]*pmi;
        if (wq != 0.f){
          float t0 = d - rbase;
          float fv = __expf(-4.f*t0*t0);        // exp(-ETA*(d-r_0)^2)
          float gv = __expf(2.116129f*t0)*C2;   // exp(8*STEP*t0)*C2  (recurrence factor)
          #pragma unroll
          for (int r=0;r<8;r++){ acc[r] += wq*fv; fv *= gv; gv *= C1; }
        }
      }
    }
    #pragma unroll
    for (int r=0;r<8;r++) qr[w][i][r] = acc[r];
  }
  __syncthreads();
  if (tid < 64){
    int g = m*64+i;
    float e = 0.f;
    #pragma unroll
    for (int k=0;k<8;k++) e += esp8[k][i];
    feat[(size_t)g*FK + 417] = (_Float16)(e * pms[i]);
  }
  if (tid < 256){
    int ii = tid & 63, bg = tid >> 6;
    h8 o;
    #pragma unroll
    for (int r=0;r<8;r++) o[r] = (_Float16)(qr[bg][ii][r] + qr[bg+4][ii][r]);
    *reinterpret_cast<h8*>(feat + (size_t)(m*64+ii)*FK + 384 + bg*8) = o;
  }
}

// ---------------- screened Coulomb + energy + outputs ----------------
__global__ void final_kernel(const float* __restrict__ dbuf, const float* __restrict__ q,
                             const float* __restrict__ pmf, const float* __restrict__ ae,
                             const int* __restrict__ species, float* __restrict__ out){
  int m = blockIdx.x, a = threadIdx.x, g = m*64+a;
  __shared__ float qs[64], pms[64];
  qs[a]=q[g]; pms[a]=pmf[g];
  __syncthreads();
  float acc=0.f;
  const float* dr = dbuf + (size_t)m*4096;
  for (int b=0;b<64;b++){
    if (b==a) continue;
    float d = dr[b*64+a];
    float sgm = 1.f/(1.f+__expf(-(d-2.2f)*8.5f));
    acc += qs[b]*pms[b]*sgm/d;
  }
  float e = 0.5f*qs[a]*pms[a]*acc;          // triu(k=1) sum of symmetric matrix
  float aea = pms[a]>0.f ? ae[g] : 0.f;
  float tot = wsum(e + aea);
  if (a == 0) out[NFLAT + m] = tot;
  out[g] = (float)species[g];
  out[NFLAT + NMOL + g] = qs[a];
}

extern "C" void kernel_launch(void* const* d_in, const int* in_sizes, int n_in,
                              void* d_out, int out_size, void* d_ws, size_t ws_size,
                              hipStream_t stream){
  const int*   species = (const int*)d_in[0];
  const float* coord   = (const float*)d_in[1];
  const float* netq    = (const float*)d_in[2];
  const float* aev     = (const float*)d_in[3];
  const float* cW[4] = {(const float*)d_in[4],(const float*)d_in[6],(const float*)d_in[8],(const float*)d_in[10]};
  const float* cB[4] = {(const float*)d_in[5],(const float*)d_in[7],(const float*)d_in[9],(const float*)d_in[11]};
  const float* aW[4] = {(const float*)d_in[12],(const float*)d_in[14],(const float*)d_in[16],(const float*)d_in[18]};
  const float* aB[4] = {(const float*)d_in[13],(const float*)d_in[15],(const float*)d_in[17],(const float*)d_in[19]};

  // workspace layout (float units; fp16 regions counted as elems/2, all 16B-aligned)
  float* f = (float*)d_ws;
  size_t o = 0;
  float* dbuf  = f + o; o += (size_t)NMOL*4096;
  float* sig   = f + o; o += NFLAT;
  float* invj  = f + o; o += NFLAT;
  float* pmf   = f + o; o += NFLAT;
  float* q     = f + o; o += NFLAT;
  float* chi   = f + o; o += NFLAT;
  _Float16* feat = (_Float16*)(f + o); o += (size_t)NFLAT*FK/2;
  _Float16* h0h  = (_Float16*)(f + o); o += (size_t)MPAD*D0/2;
  _Float16* h1h  = (_Float16*)(f + o); o += (size_t)MPAD*D1/2;
  _Float16* h2h  = h0h;   // layer2 writes over h0 (already consumed)
  // Wt[i]: [4][KT][N][32] fp16
  const int KT_[3] = {14, 8, 6};
  const int N_[3]  = {D0, D1, D2};
  _Float16* wt[6];
  for (int i=0;i<6;i++){
    wt[i] = (_Float16*)(f + o);
    o += (size_t)4*KT_[i%3]*N_[i%3]*32/2;
  }
  int* meta    = (int*)(f + o); o += 64;
  int* idxarr  = (int*)(f + o); o += MPAD;
  int* blkhist = (int*)(f + o); o += NMOL*4;
  int* blkoff  = (int*)(f + o); o += NMOL*4;

  // ---- one-time prep (per launch) ----
  cvt_aev_kernel<<<dim3(NFLAT/4), 256, 0, stream>>>(aev, feat);
  for (int i=0;i<6;i++){
    const float* Wsrc = (i<3) ? cW[i] : aW[i-3];
    int li = i%3;
    int K = (li==0) ? 418 : (li==1 ? D0 : D1);
    int N = N_[li], KT = KT_[li];
    wtrans_kernel<<<dim3((N*KT+255)/256, 4), 256, 0, stream>>>(Wsrc, wt[i], K, N, KT);
  }
  prep_kernel<<<dim3(NMOL), 256, 0, stream>>>(species, coord, dbuf, sig, invj, pmf, blkhist);
  plan_kernel<<<dim3(1), 64, 0, stream>>>(blkhist, meta, blkoff);
  scatter_kernel<<<dim3(NMOL), 64, 0, stream>>>(species, blkoff, idxarr);

  for (int pass=0; pass<3; ++pass){
    int wb = (pass<2) ? 0 : 3;
    const float* const* Bp = (pass<2) ? cB : aB;
    gemm_cb<1,8,14><<<dim3(516,2), 256, 0, stream>>>(nullptr, feat, idxarr, meta,
                                                     wt[wb+0], Bp[0], h0h, D0, 1);
    gemm_cb<0,6, 8><<<dim3(516,2), 256, 0, stream>>>(h0h, nullptr, idxarr, meta,
                                                     wt[wb+1], Bp[1], h1h, D1, 1);
    gemm_cb<0,5, 6><<<dim3(516,2), 256, 0, stream>>>(h1h, nullptr, idxarr, meta,
                                                     wt[wb+2], Bp[2], h2h, D2, 1);
    layer3_kernel<<<dim3(MPAD/4), 256, 0, stream>>>(h2h, idxarr, meta, (pass<2)?cW[3]:aW[3],
                                                    (pass<2)?cB[3]:aB[3], chi);
    if (pass < 2)
      iter_kernel<<<dim3(NMOL), 512, 0, stream>>>(chi, invj, pmf, netq, dbuf, sig, q, feat);
  }
  final_kernel<<<dim3(NMOL), 64, 0, stream>>>(dbuf, q, pmf, chi, species, (float*)d_out);
}